// Round 7
// baseline (113.462 us; speedup 1.0000x reference)
//
#include <hip/hip_runtime.h>

typedef unsigned int u32;
typedef unsigned short u16;
typedef __fp16 h2 __attribute__((ext_vector_type(2)));
typedef __fp16 f16x8 __attribute__((ext_vector_type(8)));
typedef float f32x4 __attribute__((ext_vector_type(4)));

#define DEVFN static __device__ __forceinline__

DEVFN u32 pkh(float a, float b) {
  return __builtin_bit_cast(u32, __builtin_amdgcn_cvt_pkrtz(a, b));
}
DEVFN u16 f2h(float f) { __fp16 h = (__fp16)f; return __builtin_bit_cast(u16, h); }

#if __has_builtin(__builtin_amdgcn_fdot2)
DEVFN float dot2u(u32 a, u32 b, float c) {
  return __builtin_amdgcn_fdot2(__builtin_bit_cast(h2, a),
                                __builtin_bit_cast(h2, b), c, false);
}
#else
DEVFN float dot2u(u32 a, u32 b, float c) {
  h2 x = __builtin_bit_cast(h2, a), y = __builtin_bit_cast(h2, b);
  return c + (float)x[0] * (float)y[0] + (float)x[1] * (float)y[1];
}
#endif

DEVFN uint4 cvt8h(const float* p) {
  f32x4 v0 = *(const f32x4*)p;
  f32x4 v1 = *(const f32x4*)(p + 4);
  uint4 o;
  o.x = pkh(v0.x, v0.y); o.y = pkh(v0.z, v0.w);
  o.z = pkh(v1.x, v1.y); o.w = pkh(v1.z, v1.w);
  return o;
}

DEVFN void gld16(const u16* g, u16* l) {
  __builtin_amdgcn_global_load_lds(
      (const __attribute__((address_space(1))) u32*)g,
      (__attribute__((address_space(3))) u32*)l, 16, 0, 0);
}

// f32 -> f16 pre-convert: x (8388608) -> xb, w_qk (524288) -> wqb
__global__ __launch_bounds__(256) void cvt3(
    const float* __restrict__ x, const float* __restrict__ wqk,
    u16* __restrict__ xb, u16* __restrict__ wqb) {
  const size_t e = ((size_t)blockIdx.x * 256 + threadIdx.x) * 8;
  const float* s;
  u16* d;
  if (e < 8388608) { s = x + e; d = xb + e; }
  else { s = wqk + (e - 8388608); d = wqb + (e - 8388608); }
  *(uint4*)d = cvt8h(s);
}

// W2[o][h*56+p] = sum_c w_proj[o][h*64+c] * w_corr[c][p]  (f16, pads 0)
// cvec[o] = b_proj[o] + sum_c' w_proj[o][c'] * b_corr[c'&63]
__global__ __launch_bounds__(512) void w2prep(
    const float* __restrict__ wp, const float* __restrict__ wc,
    const float* __restrict__ bc, const float* __restrict__ bp,
    u16* __restrict__ W2, float* __restrict__ cvec) {
  __shared__ float wcl[64 * 49];
  __shared__ float wpl[512];
  const int o = blockIdx.x, tid = threadIdx.x;
  for (int i = tid; i < 64 * 49; i += 512) wcl[i] = wc[i];
  wpl[tid] = wp[o * 512 + tid];
  __syncthreads();
  if (tid < 448) {
    int hh = tid / 56, p = tid % 56;
    if (p < 49) {
      float s = 0.f;
#pragma unroll
      for (int c = 0; c < 64; ++c) s += wpl[hh * 64 + c] * wcl[c * 49 + p];
      W2[o * 448 + tid] = f2h(s);
    } else {
      W2[o * 448 + tid] = 0;
    }
  } else if (tid == 448) {
    float s = bp[o];
    for (int c = 0; c < 512; ++c) s += wpl[c] * bc[c & 63];
    cvec[o] = s;
  }
}

// C = A @ B^T, A:[M,K] f16, B:[N,K] f16, both gld16-staged. K%32==0.
// MODE 0: L2-normalize each aligned 64-col group; write f16 PLANAR qf
//         [sel][b][t][h][1024px][64]  (fr = ((sel*2+b)*8+t)*8+h); Nn=1024
// MODE 1: add f32 bias[col]; Out = f32 row-major [M][Nn]
// Tiles: BM=BN=128, BK=32; 4 waves (2x2), per-wave 4x4 frags of mfma 16x16x32 f16.
template <int MODE, int TN>
__global__ __launch_bounds__(256) void gemm(
    const u16* __restrict__ A, const u16* __restrict__ B,
    const float* __restrict__ bias, void* __restrict__ Out_,
    int Nn, int K) {
  __shared__ u16 As[128 * 32];
  __shared__ u16 Bs[128 * 32];
  const int tid = threadIdx.x;
  const int lane = tid & 63;
  const int w = tid >> 6;
  const int wm = w >> 1, wn = w & 1;
  const int nwg = (int)gridDim.x;
  const int wg = ((int)blockIdx.x & 7) * (nwg >> 3) + ((int)blockIdx.x >> 3);
  const int tm = wg / TN, tn = wg % TN;

  const int sr = w * 32 + (lane >> 2);
  const int sc = (lane & 3) << 3;
  u16* lA = As + w * 1024;
  u16* lB = Bs + w * 1024;
  const u16* gA = A + (size_t)(tm * 128 + sr) * K + sc;
  const u16* gB = B + (size_t)(tn * 128 + sr) * K + sc;

  const u16* rA = As + (wm * 64 + (lane & 15)) * 32 + ((lane >> 4) << 3);
  const u16* rB = Bs + (wn * 64 + (lane & 15)) * 32 + ((lane >> 4) << 3);

  f32x4 acc[4][4] = {};

  const int KT = K >> 5;
  for (int kt = 0; kt < KT; ++kt) {
    __syncthreads();  // prior iteration's LDS reads retired
    gld16(gA + kt * 32, lA);
    gld16(gA + kt * 32 + (size_t)16 * K, lA + 512);
    gld16(gB + kt * 32, lB);
    gld16(gB + kt * 32 + (size_t)16 * K, lB + 512);
    __syncthreads();  // compiler drains vmcnt before barrier
    f16x8 af[4], bf[4];
#pragma unroll
    for (int i = 0; i < 4; ++i) af[i] = *(const f16x8*)(rA + i * 512);
#pragma unroll
    for (int i = 0; i < 4; ++i) bf[i] = *(const f16x8*)(rB + i * 512);
#pragma unroll
    for (int mi = 0; mi < 4; ++mi)
#pragma unroll
      for (int ni = 0; ni < 4; ++ni)
        acc[mi][ni] = __builtin_amdgcn_mfma_f32_16x16x32_f16(af[mi], bf[ni],
                                                             acc[mi][ni], 0, 0, 0);
  }

  // C/D layout (HW-verified): col = lane&15, row = (lane>>4)*4 + r
  const int rowBase = tm * 128 + wm * 64 + ((lane >> 4) << 2);
  const int colBase = tn * 128 + wn * 64 + (lane & 15);

  if (MODE == 1) {
    float* Out = (float*)Out_;
    float bv[4];
#pragma unroll
    for (int ni = 0; ni < 4; ++ni) bv[ni] = bias[colBase + ni * 16];
#pragma unroll
    for (int mi = 0; mi < 4; ++mi)
#pragma unroll
      for (int r = 0; r < 4; ++r) {
        size_t ro = (size_t)(rowBase + mi * 16 + r) * Nn;
#pragma unroll
        for (int ni = 0; ni < 4; ++ni)
          Out[ro + colBase + ni * 16] = acc[mi][ni][r] + bv[ni];
      }
  } else {
    u16* Out = (u16*)Out_;
    const int sel = colBase >> 9;
    const int hh = (colBase >> 6) & 7;
    const int ddb = lane & 15;
#pragma unroll
    for (int mi = 0; mi < 4; ++mi)
#pragma unroll
      for (int r = 0; r < 4; ++r) {
        float s = acc[mi][0][r] * acc[mi][0][r] + acc[mi][1][r] * acc[mi][1][r] +
                  acc[mi][2][r] * acc[mi][2][r] + acc[mi][3][r] * acc[mi][3][r];
        s += __shfl_xor(s, 1);
        s += __shfl_xor(s, 2);
        s += __shfl_xor(s, 4);
        s += __shfl_xor(s, 8);
        float inv = 1.0f / fmaxf(sqrtf(s), 1e-12f);
        const int m = rowBase + mi * 16 + r;
        const int bb = m >> 13, tt = (m >> 10) & 7, pix = m & 1023;
        const int fr = ((sel * 2 + bb) * 8 + tt) * 8 + hh;
        size_t base = (((size_t)fr) << 16) + (size_t)pix * 64 + ddb;
#pragma unroll
        for (int ni = 0; ni < 4; ++ni)
          Out[base + ni * 16] = f2h(acc[mi][ni][r] * inv);
      }
  }
}

// Dots-only cost volume, channel-split (2 threads/px, 32ch each).
// qf planar [sel][b][t][h][1024px][64] f16. Writes corr[token][448] f16
// (col = h*56+p, p<49 data, 49..55 zero-pad).
// 1024 blocks (128 frames x 8 groups of 4 q-rows) x 256 threads.
// LDS: 10 staged k-rows x 32px x 128B = 40960B -> 4 blocks/CU.
__global__ __launch_bounds__(256) void dots(
    const u16* __restrict__ qf, u16* __restrict__ corr) {
  __shared__ __align__(16) u16 kst[320 * 64];  // 40 KB, XOR-swizzled 128B rows
  const int tid = threadIdx.x;
  const int bid = ((int)blockIdx.x & 7) * 128 + ((int)blockIdx.x >> 3);  // XCD
  const int fr = bid >> 3, grp = bid & 7;
  const int h = fr & 7, t = (fr >> 3) & 7, b = fr >> 6;
  const int t1 = (t < 7) ? t + 1 : 7;
  const int y0 = grp * 4;

  // stage k rows y0-3 .. y0+6 (zero OOB), swizzle byte ^= (pl&7)<<4
  const u16* kbase = qf + (((size_t)(((2 + b) * 8 + t1) * 8 + h)) << 16);
  {
    const int ppx = tid >> 3;        // 0..31
    const int slot = tid & 7;        // 16B slot
#pragma unroll
    for (int pass = 0; pass < 10; ++pass) {
      int gy = y0 - 3 + pass;
      uint4 v = make_uint4(0, 0, 0, 0);
      if ((unsigned)gy < 32u)
        v = *(const uint4*)(kbase + (size_t)(gy * 32 + ppx) * 64 + slot * 8);
      int pl = pass * 32 + ppx;
      *(uint4*)((char*)kst + pl * 128 + ((slot * 16) ^ ((pl & 7) << 4))) = v;
    }
  }

  // q half into registers (lane pair 2i/2i+1 = same px, halves 0/1)
  const int pxl = tid >> 1, half = tid & 1;
  const int px = grp * 128 + pxl;
  const int x = px & 31, yl = pxl >> 5;  // yl 0..3
  const u16* qp = qf + (((size_t)fr) << 16) + (size_t)px * 64 + half * 32;
  u32 qw[16];
#pragma unroll
  for (int j = 0; j < 4; ++j) {
    uint4 v = *(const uint4*)(qp + j * 8);
    qw[j * 4 + 0] = v.x; qw[j * 4 + 1] = v.y;
    qw[j * 4 + 2] = v.z; qw[j * 4 + 3] = v.w;
  }
  __syncthreads();

  const size_t tokb = (size_t)((b * 8 + t) * 1024 + px) * 448 + h * 56;
  for (int du = 0; du < 7; ++du) {
    const int rl = yl + du;  // staged row index 0..9
#pragma unroll
    for (int dv = 0; dv < 7; ++dv) {
      int xx = x + dv - 3;
      int xc = xx < 0 ? 0 : (xx > 31 ? 31 : xx);
      int pl = rl * 32 + xc;
      const char* kr = (const char*)kst + pl * 128;
      const int swz = (pl & 7) << 4;
      float s0 = 0.f, s1 = 0.f, s2 = 0.f, s3 = 0.f;
#pragma unroll
      for (int j = 0; j < 4; ++j) {
        uint4 v = *(const uint4*)(kr + ((half * 64 + j * 16) ^ swz));
        s0 = dot2u(qw[j * 4 + 0], v.x, s0);
        s1 = dot2u(qw[j * 4 + 1], v.y, s1);
        s2 = dot2u(qw[j * 4 + 2], v.z, s2);
        s3 = dot2u(qw[j * 4 + 3], v.w, s3);
      }
      float s = (s0 + s1) + (s2 + s3);
      s += __shfl_xor(s, 1);                 // combine channel halves
      s = ((unsigned)xx < 32u) ? s : 0.f;    // OOB col -> 0
      int p = du * 7 + dv;
      if ((p & 1) == half) corr[tokb + p] = f2h(s);  // parity-split stores
    }
  }
  // zero the K-pads p=49..55 (parity-split)
  if (half) {
#pragma unroll
    for (int i = 0; i < 4; ++i) corr[tokb + 49 + 2 * i] = 0;
  } else {
#pragma unroll
    for (int i = 0; i < 3; ++i) corr[tokb + 50 + 2 * i] = 0;
  }
}

extern "C" void kernel_launch(void* const* d_in, const int* in_sizes, int n_in,
                              void* d_out, int out_size, void* d_ws, size_t ws_size,
                              hipStream_t stream) {
  const float* x      = (const float*)d_in[0];  // [2,8192,512] f32
  const float* w_qk   = (const float*)d_in[1];  // [1024,512]   f32
  const float* w_corr = (const float*)d_in[2];  // [64,49]      f32
  const float* b_corr = (const float*)d_in[3];  // [64]         f32
  const float* w_proj = (const float*)d_in[4];  // [512,512]    f32
  const float* b_proj = (const float*)d_in[5];  // [512]        f32
  float* out = (float*)d_out;                   // [2,8192,512] f32

  // ws layout (48MB): [0,16MB) xb (f16 x), later overwritten by corr/W2/cvec;
  //                   [16MB,48MB) qf planar f16
  u16* xb   = (u16*)d_ws;
  u16* corr = xb;                                   // [16384][448] f16 = 14.68MB
  u16* W2   = xb + (size_t)16384 * 448;             // [512][448] f16 = 448KB
  float* cvec = (float*)(xb + (size_t)16384 * 448 + 512 * 448);  // 2KB
  u16* qf   = (u16*)d_ws + (size_t)16384 * 512;     // 32MB
  u16* wqb  = (u16*)d_out;                          // 1MB scratch, overwritten

  // f32 -> f16 (x -> xb, w_qk -> wqb)
  cvt3<<<dim3(4352), dim3(256), 0, stream>>>(x, w_qk, xb, wqb);
  // qk projection + per-head L2 norm -> planar f16 qf
  gemm<0, 8><<<dim3(1024), dim3(256), 0, stream>>>(xb, wqb, nullptr, qf,
                                                   1024, 512);
  // cost-volume dots -> corr [16384][448] (overwrites xb)
  dots<<<dim3(1024), dim3(256), 0, stream>>>(qf, corr);
  // fused corr->out weights: W2 = w_proj_h @ w_corr, cvec = folded biases
  w2prep<<<dim3(512), dim3(512), 0, stream>>>(w_proj, w_corr, b_corr, b_proj,
                                              W2, cvec);
  // out = corr @ W2^T + cvec  (K=448)
  gemm<1, 4><<<dim3(512), dim3(256), 0, stream>>>(corr, W2, cvec, out,
                                                  512, 448);
}

// Round 8
// 91.368 us; speedup vs baseline: 1.2418x; 1.2418x over previous
//
#include <hip/hip_runtime.h>

typedef unsigned int u32;
typedef unsigned short u16;
typedef __fp16 h2 __attribute__((ext_vector_type(2)));
typedef __fp16 f16x8 __attribute__((ext_vector_type(8)));
typedef float f32x4 __attribute__((ext_vector_type(4)));

#define DEVFN static __device__ __forceinline__

DEVFN u32 pkh(float a, float b) {
  return __builtin_bit_cast(u32, __builtin_amdgcn_cvt_pkrtz(a, b));
}
DEVFN u16 f2h(float f) { __fp16 h = (__fp16)f; return __builtin_bit_cast(u16, h); }

#if __has_builtin(__builtin_amdgcn_fdot2)
DEVFN float dot2u(u32 a, u32 b, float c) {
  return __builtin_amdgcn_fdot2(__builtin_bit_cast(h2, a),
                                __builtin_bit_cast(h2, b), c, false);
}
#else
DEVFN float dot2u(u32 a, u32 b, float c) {
  h2 x = __builtin_bit_cast(h2, a), y = __builtin_bit_cast(h2, b);
  return c + (float)x[0] * (float)y[0] + (float)x[1] * (float)y[1];
}
#endif

DEVFN uint4 cvt8h(const float* p) {
  f32x4 v0 = *(const f32x4*)p;
  f32x4 v1 = *(const f32x4*)(p + 4);
  uint4 o;
  o.x = pkh(v0.x, v0.y); o.y = pkh(v0.z, v0.w);
  o.z = pkh(v1.x, v1.y); o.w = pkh(v1.z, v1.w);
  return o;
}

DEVFN void gld16(const u16* g, u16* l) {
  __builtin_amdgcn_global_load_lds(
      (const __attribute__((address_space(1))) u32*)g,
      (__attribute__((address_space(3))) u32*)l, 16, 0, 0);
}

// f32 -> f16 pre-convert: x (8388608) -> xb, w_qk (524288) -> wqb
__global__ __launch_bounds__(256) void cvt3(
    const float* __restrict__ x, const float* __restrict__ wqk,
    u16* __restrict__ xb, u16* __restrict__ wqb) {
  const size_t e = ((size_t)blockIdx.x * 256 + threadIdx.x) * 8;
  const float* s;
  u16* d;
  if (e < 8388608) { s = x + e; d = xb + e; }
  else { s = wqk + (e - 8388608); d = wqb + (e - 8388608); }
  *(uint4*)d = cvt8h(s);
}

// W2[o][h*64 + du*8 + dv] = sum_c w_proj[o][h*64+c] * w_corr[c][du*7+dv]
// (du,dv <= 6; pad slots du==7 or dv==7 are 0).  cvec[o] = b_proj[o] +
// sum_c' w_proj[o][c'] * b_corr[c'&63]
__global__ __launch_bounds__(512) void w2prep(
    const float* __restrict__ wp, const float* __restrict__ wc,
    const float* __restrict__ bc, const float* __restrict__ bp,
    u16* __restrict__ W2, float* __restrict__ cvec) {
  __shared__ float wcl[64 * 49];
  __shared__ float wpl[512];
  const int o = blockIdx.x, tid = threadIdx.x;
  for (int i = tid; i < 64 * 49; i += 512) wcl[i] = wc[i];
  wpl[tid] = wp[o * 512 + tid];
  __syncthreads();
  const int hh = tid >> 6, r = tid & 63, du = r >> 3, dv = r & 7;
  float s = 0.f;
  if (du < 7 && dv < 7) {
#pragma unroll
    for (int c = 0; c < 64; ++c) s += wpl[hh * 64 + c] * wcl[c * 49 + du * 7 + dv];
  }
  W2[o * 512 + tid] = f2h(s);
  if (tid < 64) {
    float p = 0.f;
#pragma unroll
    for (int g = 0; g < 8; ++g) p += wpl[g * 64 + tid];
    p *= bc[tid];
    p += __shfl_xor(p, 1); p += __shfl_xor(p, 2); p += __shfl_xor(p, 4);
    p += __shfl_xor(p, 8); p += __shfl_xor(p, 16); p += __shfl_xor(p, 32);
    if (tid == 0) cvec[o] = p + bp[o];
  }
}

// C = A @ B^T, A:[M,K] f16, B:[N,K] f16, both gld16-staged. K%32==0.
// MODE 0: L2-normalize each aligned 64-col group; write f16 PLANAR qf
//         [sel][b][t][h][1024px][64]  (fr = ((sel*2+b)*8+t)*8+h); Nn=1024
// MODE 1: add f32 bias[col]; Out = f32 row-major [M][Nn]
// Tiles: BM=BN=128, BK=32; 4 waves (2x2), per-wave 4x4 frags of mfma 16x16x32 f16.
template <int MODE, int TN>
__global__ __launch_bounds__(256) void gemm(
    const u16* __restrict__ A, const u16* __restrict__ B,
    const float* __restrict__ bias, void* __restrict__ Out_,
    int Nn, int K) {
  __shared__ u16 As[128 * 32];
  __shared__ u16 Bs[128 * 32];
  const int tid = threadIdx.x;
  const int lane = tid & 63;
  const int w = tid >> 6;
  const int wm = w >> 1, wn = w & 1;
  const int nwg = (int)gridDim.x;
  const int wg = ((int)blockIdx.x & 7) * (nwg >> 3) + ((int)blockIdx.x >> 3);
  const int tm = wg / TN, tn = wg % TN;

  const int sr = w * 32 + (lane >> 2);
  const int sc = (lane & 3) << 3;
  u16* lA = As + w * 1024;
  u16* lB = Bs + w * 1024;
  const u16* gA = A + (size_t)(tm * 128 + sr) * K + sc;
  const u16* gB = B + (size_t)(tn * 128 + sr) * K + sc;

  const u16* rA = As + (wm * 64 + (lane & 15)) * 32 + ((lane >> 4) << 3);
  const u16* rB = Bs + (wn * 64 + (lane & 15)) * 32 + ((lane >> 4) << 3);

  f32x4 acc[4][4] = {};

  const int KT = K >> 5;
  for (int kt = 0; kt < KT; ++kt) {
    __syncthreads();  // prior iteration's LDS reads retired
    gld16(gA + kt * 32, lA);
    gld16(gA + kt * 32 + (size_t)16 * K, lA + 512);
    gld16(gB + kt * 32, lB);
    gld16(gB + kt * 32 + (size_t)16 * K, lB + 512);
    __syncthreads();  // compiler drains vmcnt before barrier
    f16x8 af[4], bf[4];
#pragma unroll
    for (int i = 0; i < 4; ++i) af[i] = *(const f16x8*)(rA + i * 512);
#pragma unroll
    for (int i = 0; i < 4; ++i) bf[i] = *(const f16x8*)(rB + i * 512);
#pragma unroll
    for (int mi = 0; mi < 4; ++mi)
#pragma unroll
      for (int ni = 0; ni < 4; ++ni)
        acc[mi][ni] = __builtin_amdgcn_mfma_f32_16x16x32_f16(af[mi], bf[ni],
                                                             acc[mi][ni], 0, 0, 0);
  }

  // C/D layout (HW-verified): col = lane&15, row = (lane>>4)*4 + r
  const int rowBase = tm * 128 + wm * 64 + ((lane >> 4) << 2);
  const int colBase = tn * 128 + wn * 64 + (lane & 15);

  if (MODE == 1) {
    float* Out = (float*)Out_;
    float bv[4];
#pragma unroll
    for (int ni = 0; ni < 4; ++ni) bv[ni] = bias[colBase + ni * 16];
#pragma unroll
    for (int mi = 0; mi < 4; ++mi)
#pragma unroll
      for (int r = 0; r < 4; ++r) {
        size_t ro = (size_t)(rowBase + mi * 16 + r) * Nn;
#pragma unroll
        for (int ni = 0; ni < 4; ++ni)
          Out[ro + colBase + ni * 16] = acc[mi][ni][r] + bv[ni];
      }
  } else {
    u16* Out = (u16*)Out_;
    const int sel = colBase >> 9;
    const int hh = (colBase >> 6) & 7;
    const int ddb = lane & 15;
#pragma unroll
    for (int mi = 0; mi < 4; ++mi)
#pragma unroll
      for (int r = 0; r < 4; ++r) {
        float s = acc[mi][0][r] * acc[mi][0][r] + acc[mi][1][r] * acc[mi][1][r] +
                  acc[mi][2][r] * acc[mi][2][r] + acc[mi][3][r] * acc[mi][3][r];
        s += __shfl_xor(s, 1);
        s += __shfl_xor(s, 2);
        s += __shfl_xor(s, 4);
        s += __shfl_xor(s, 8);
        float inv = 1.0f / fmaxf(sqrtf(s), 1e-12f);
        const int m = rowBase + mi * 16 + r;
        const int bb = m >> 13, tt = (m >> 10) & 7, pix = m & 1023;
        const int fr = ((sel * 2 + bb) * 8 + tt) * 8 + hh;
        size_t base = (((size_t)fr) << 16) + (size_t)pix * 64 + ddb;
#pragma unroll
        for (int ni = 0; ni < 4; ++ni)
          Out[base + ni * 16] = f2h(acc[mi][ni][r] * inv);
      }
  }
}

// Dots-only cost volume v4: 1 thread per px-head, full 64ch, NO shfl.
// qf planar [sel][b][t][h][1024px][64] f16.
// corr[tok][512] f16, col = h*64 + du*8 + dv (du,dv<7 data; pads zero).
// 512 blocks (128 frame-heads x 4 groups of 8 q-rows) x 256 threads.
// LDS: 14 staged k-rows x 32px x 128B = 57344B -> 2 blocks/CU.
__global__ __launch_bounds__(256) void dots(
    const u16* __restrict__ qf, u16* __restrict__ corr) {
  __shared__ __align__(16) u16 kst[448 * 64];  // 56 KB, XOR-swizzled 128B rows
  const int tid = threadIdx.x;
  const int bid = ((int)blockIdx.x & 7) * 64 + ((int)blockIdx.x >> 3);  // XCD
  const int fr = bid >> 2, grp = bid & 3;
  const int h = fr & 7, t = (fr >> 3) & 7, b = fr >> 6;
  const int t1 = (t < 7) ? t + 1 : 7;
  const int y0 = grp * 8;

  // stage k rows y0-3 .. y0+10 (zero OOB), swizzle byte ^= (pl&7)<<4
  const u16* kbase = qf + (((size_t)(((2 + b) * 8 + t1) * 8 + h)) << 16);
  {
    const int ppx = tid >> 3;        // 0..31
    const int slot = tid & 7;        // 16B slot
#pragma unroll
    for (int pass = 0; pass < 14; ++pass) {
      int gy = y0 - 3 + pass;
      uint4 v = make_uint4(0, 0, 0, 0);
      if ((unsigned)gy < 32u)
        v = *(const uint4*)(kbase + (size_t)(gy * 32 + ppx) * 64 + slot * 8);
      int pl = pass * 32 + ppx;
      *(uint4*)((char*)kst + pl * 128 + ((slot * 16) ^ ((pl & 7) << 4))) = v;
    }
  }

  // q (64ch) into registers; px = grp*256 + tid (coalesced)
  const int px = grp * 256 + tid;
  const int x = tid & 31, yloc = tid >> 5;  // 8 q-rows per block
  const u16* qp = qf + (((size_t)fr) << 16) + (size_t)px * 64;
  u32 qw[32];
#pragma unroll
  for (int j = 0; j < 8; ++j) {
    uint4 v = *(const uint4*)(qp + j * 8);
    qw[j * 4 + 0] = v.x; qw[j * 4 + 1] = v.y;
    qw[j * 4 + 2] = v.z; qw[j * 4 + 3] = v.w;
  }
  __syncthreads();

  u16* mp = corr + (size_t)((b * 8 + t) * 1024 + px) * 512 + h * 64;
  for (int du = 0; du < 7; ++du) {   // rolled; all reg arrays static inside
    const int rlbase = (yloc + du) * 32;
    float f[7];
#pragma unroll
    for (int dv = 0; dv < 7; ++dv) {
      int xx = x + dv - 3;
      int xc = xx < 0 ? 0 : (xx > 31 ? 31 : xx);
      int pl = rlbase + xc;
      const char* kr = (const char*)kst + pl * 128;
      const int swz = (pl & 7) << 4;
      float s0 = 0.f, s1 = 0.f, s2 = 0.f, s3 = 0.f;
#pragma unroll
      for (int j = 0; j < 8; ++j) {
        uint4 v = *(const uint4*)(kr + ((j * 16) ^ swz));
        s0 = dot2u(qw[j * 4 + 0], v.x, s0);
        s1 = dot2u(qw[j * 4 + 1], v.y, s1);
        s2 = dot2u(qw[j * 4 + 2], v.z, s2);
        s3 = dot2u(qw[j * 4 + 3], v.w, s3);
      }
      float s = (s0 + s1) + (s2 + s3);
      f[dv] = ((unsigned)xx < 32u) ? s : 0.f;  // OOB col -> 0
    }
    uint4 o;
    o.x = pkh(f[0], f[1]); o.y = pkh(f[2], f[3]);
    o.z = pkh(f[4], f[5]); o.w = pkh(f[6], 0.f);
    *(uint4*)(mp + du * 8) = o;   // one aligned 16B store per du
  }
  *(uint4*)(mp + 56) = make_uint4(0, 0, 0, 0);  // du==7 pad row
}

extern "C" void kernel_launch(void* const* d_in, const int* in_sizes, int n_in,
                              void* d_out, int out_size, void* d_ws, size_t ws_size,
                              hipStream_t stream) {
  const float* x      = (const float*)d_in[0];  // [2,8192,512] f32
  const float* w_qk   = (const float*)d_in[1];  // [1024,512]   f32
  const float* w_corr = (const float*)d_in[2];  // [64,49]      f32
  const float* b_corr = (const float*)d_in[3];  // [64]         f32
  const float* w_proj = (const float*)d_in[4];  // [512,512]    f32
  const float* b_proj = (const float*)d_in[5];  // [512]        f32
  float* out = (float*)d_out;                   // [2,8192,512] f32

  // ws (48MB): [0,16MB) xb (f16 x) -> later corr [16384][512];
  //            [16MB,48MB) qf -> later W2 (512KB) + cvec (after dots)
  u16* xb   = (u16*)d_ws;
  u16* corr = xb;                                  // aliases xb (dead after gemm1)
  u16* qf   = (u16*)d_ws + (size_t)16384 * 512;    // 32MB
  u16* W2   = qf;                                  // aliases qf (dead after dots)
  float* cvec = (float*)(qf + (size_t)512 * 512);
  u16* wqb  = (u16*)d_out;                         // 1MB scratch, overwritten

  // f32 -> f16 (x -> xb, w_qk -> wqb)
  cvt3<<<dim3(4352), dim3(256), 0, stream>>>(x, w_qk, xb, wqb);
  // qk projection + per-head L2 norm -> planar f16 qf
  gemm<0, 8><<<dim3(1024), dim3(256), 0, stream>>>(xb, wqb, nullptr, qf,
                                                   1024, 512);
  // cost-volume dots -> corr [16384][512] (overwrites xb)
  dots<<<dim3(512), dim3(256), 0, stream>>>(qf, corr);
  // fused corr->out weights (into qf region, safe after dots)
  w2prep<<<dim3(512), dim3(512), 0, stream>>>(w_proj, w_corr, b_corr, b_proj,
                                              W2, cvec);
  // out = corr @ W2^T + cvec  (K=512)
  gemm<1, 4><<<dim3(512), dim3(256), 0, stream>>>(corr, W2, cvec, out,
                                                  512, 512);
}

// Round 9
// 83.728 us; speedup vs baseline: 1.3551x; 1.0912x over previous
//
#include <hip/hip_runtime.h>

typedef unsigned int u32;
typedef unsigned short u16;
typedef __fp16 h2 __attribute__((ext_vector_type(2)));
typedef __fp16 f16x8 __attribute__((ext_vector_type(8)));
typedef float f32x4 __attribute__((ext_vector_type(4)));

#define DEVFN static __device__ __forceinline__

DEVFN u32 pkh(float a, float b) {
  return __builtin_bit_cast(u32, __builtin_amdgcn_cvt_pkrtz(a, b));
}
DEVFN u16 f2h(float f) { __fp16 h = (__fp16)f; return __builtin_bit_cast(u16, h); }

#if __has_builtin(__builtin_amdgcn_fdot2)
DEVFN float dot2u(u32 a, u32 b, float c) {
  return __builtin_amdgcn_fdot2(__builtin_bit_cast(h2, a),
                                __builtin_bit_cast(h2, b), c, false);
}
#else
DEVFN float dot2u(u32 a, u32 b, float c) {
  h2 x = __builtin_bit_cast(h2, a), y = __builtin_bit_cast(h2, b);
  return c + (float)x[0] * (float)y[0] + (float)x[1] * (float)y[1];
}
#endif

// pack 2 f32x4 -> 8 f16
DEVFN uint4 pk8(f32x4 lo, f32x4 hi) {
  uint4 o;
  o.x = pkh(lo.x, lo.y); o.y = pkh(lo.z, lo.w);
  o.z = pkh(hi.x, hi.y); o.w = pkh(hi.z, hi.w);
  return o;
}

DEVFN void gld16(const u16* g, u16* l) {
  __builtin_amdgcn_global_load_lds(
      (const __attribute__((address_space(1))) u32*)g,
      (__attribute__((address_space(3))) u32*)l, 16, 0, 0);
}

// W2[o][h*64 + du*8 + dv] = sum_c w_proj[o][h*64+c] * w_corr[c][du*7+dv]
// (du,dv <= 6; pad slots du==7 or dv==7 are 0).  cvec[o] = b_proj[o] +
// sum_c' w_proj[o][c'] * b_corr[c'&63]
__global__ __launch_bounds__(512) void w2prep(
    const float* __restrict__ wp, const float* __restrict__ wc,
    const float* __restrict__ bc, const float* __restrict__ bp,
    u16* __restrict__ W2, float* __restrict__ cvec) {
  __shared__ float wcl[64 * 49];
  __shared__ float wpl[512];
  const int o = blockIdx.x, tid = threadIdx.x;
  for (int i = tid; i < 64 * 49; i += 512) wcl[i] = wc[i];
  wpl[tid] = wp[o * 512 + tid];
  __syncthreads();
  const int hh = tid >> 6, r = tid & 63, du = r >> 3, dv = r & 7;
  float s = 0.f;
  if (du < 7 && dv < 7) {
#pragma unroll
    for (int c = 0; c < 64; ++c) s += wpl[hh * 64 + c] * wcl[c * 49 + du * 7 + dv];
  }
  W2[o * 512 + tid] = f2h(s);
  if (tid < 64) {
    float p = 0.f;
#pragma unroll
    for (int g = 0; g < 8; ++g) p += wpl[g * 64 + tid];
    p *= bc[tid];
    p += __shfl_xor(p, 1); p += __shfl_xor(p, 2); p += __shfl_xor(p, 4);
    p += __shfl_xor(p, 8); p += __shfl_xor(p, 16); p += __shfl_xor(p, 32);
    if (tid == 0) cvec[o] = p + bp[o];
  }
}

// C = A @ B^T. Single-barrier double-buffered K-loop (T3-minimum + T14 split):
//   issue tile t+1 loads -> ds_read/MFMA tile t -> (cvt+ds_write t+1) -> barrier
// AF32/BF32: operand f32, reg-staged with in-loop f32->f16 convert (fuses cvt).
// else f16 via global_load_lds. K%32==0.
// MODE 0: L2-normalize each aligned 64-col group; write f16 PLANAR qf
//         [sel][b][t][h][1024px][64]  (fr = ((sel*2+b)*8+t)*8+h); Nn=1024
// MODE 1: add f32 bias[col]; Out = f32 row-major [M][Nn]
// Tiles: BM=BN=128, BK=32; 4 waves (2x2), per-wave 4x4 frags of mfma 16x16x32 f16.
template <int MODE, int AF32, int BF32, int TN>
__global__ __launch_bounds__(256) void gemm(
    const void* __restrict__ A_, const void* __restrict__ B_,
    const float* __restrict__ bias, void* __restrict__ Out_,
    int Nn, int K) {
  __shared__ u16 As[2][128 * 32];
  __shared__ u16 Bs[2][128 * 32];
  const int tid = threadIdx.x;
  const int lane = tid & 63;
  const int w = tid >> 6;
  const int wm = w >> 1, wn = w & 1;
  const int nwg = (int)gridDim.x;
  const int wg = ((int)blockIdx.x & 7) * (nwg >> 3) + ((int)blockIdx.x >> 3);
  const int tm = wg / TN, tn = wg % TN;

  const float* Af = (const float*)A_;
  const float* Bf = (const float*)B_;
  const u16* Ah = (const u16*)A_;
  const u16* Bh = (const u16*)B_;

  // gld16 geometry (f16 operands): wave w covers rows w*32..w*32+31
  const int sr = w * 32 + (lane >> 2);
  const int sc = (lane & 3) << 3;
  const u16* gA = Ah + (size_t)(tm * 128 + sr) * K + sc;
  const u16* gB = Bh + (size_t)(tn * 128 + sr) * K + sc;
  u16* lA = &As[0][0] + w * 1024;  // + nxt*4096
  u16* lB = &Bs[0][0] + w * 1024;

  // reg-staging geometry (f32 operands): rows {rr, rr+64}, 8 k-elems
  const int rr = tid >> 2;
  const int rc = (tid & 3) << 3;
  const size_t offA0 = (size_t)(tm * 128 + rr) * K + rc;
  const size_t offB0 = (size_t)(tn * 128 + rr) * K + rc;
  u16* sA0 = &As[0][0] + rr * 32 + rc;   // + nxt*4096
  u16* sB0 = &Bs[0][0] + rr * 32 + rc;

  // fragment read bases (+ cur*4096)
  const u16* rA = &As[0][0] + (wm * 64 + (lane & 15)) * 32 + ((lane >> 4) << 3);
  const u16* rB = &Bs[0][0] + (wn * 64 + (lane & 15)) * 32 + ((lane >> 4) << 3);

  f32x4 acc[4][4] = {};
  const int KT = K >> 5;

  // ---- prologue: stage tile 0 into buffer 0 ----
  if (AF32) {
    f32x4 p0 = *(const f32x4*)(Af + offA0);
    f32x4 p1 = *(const f32x4*)(Af + offA0 + 4);
    f32x4 p2 = *(const f32x4*)(Af + offA0 + (size_t)64 * K);
    f32x4 p3 = *(const f32x4*)(Af + offA0 + (size_t)64 * K + 4);
    *(uint4*)sA0 = pk8(p0, p1);
    *(uint4*)(sA0 + 2048) = pk8(p2, p3);   // row +64 => +64*32 elems
  } else {
    gld16(gA, lA);
    gld16(gA + (size_t)16 * K, lA + 512);
  }
  if (BF32) {
    f32x4 p0 = *(const f32x4*)(Bf + offB0);
    f32x4 p1 = *(const f32x4*)(Bf + offB0 + 4);
    f32x4 p2 = *(const f32x4*)(Bf + offB0 + (size_t)64 * K);
    f32x4 p3 = *(const f32x4*)(Bf + offB0 + (size_t)64 * K + 4);
    *(uint4*)sB0 = pk8(p0, p1);
    *(uint4*)(sB0 + 2048) = pk8(p2, p3);
  } else {
    gld16(gB, lB);
    gld16(gB + (size_t)16 * K, lB + 512);
  }
  __syncthreads();

  // ---- main loop: one barrier per K-step ----
  for (int kt = 0; kt < KT; ++kt) {
    const int cur = kt & 1, nxt = cur ^ 1;
    const bool more = (kt + 1) < KT;
    f32x4 a0, a1, a2, a3, b0, b1, b2, b3;
    if (more) {
      const int off = (kt + 1) * 32;
      if (AF32) {
        a0 = *(const f32x4*)(Af + offA0 + off);
        a1 = *(const f32x4*)(Af + offA0 + off + 4);
        a2 = *(const f32x4*)(Af + offA0 + off + (size_t)64 * K);
        a3 = *(const f32x4*)(Af + offA0 + off + (size_t)64 * K + 4);
      } else {
        gld16(gA + off, lA + nxt * 4096);
        gld16(gA + off + (size_t)16 * K, lA + nxt * 4096 + 512);
      }
      if (BF32) {
        b0 = *(const f32x4*)(Bf + offB0 + off);
        b1 = *(const f32x4*)(Bf + offB0 + off + 4);
        b2 = *(const f32x4*)(Bf + offB0 + off + (size_t)64 * K);
        b3 = *(const f32x4*)(Bf + offB0 + off + (size_t)64 * K + 4);
      } else {
        gld16(gB + off, lB + nxt * 4096);
        gld16(gB + off + (size_t)16 * K, lB + nxt * 4096 + 512);
      }
    }

    f16x8 af[4], bf[4];
#pragma unroll
    for (int i = 0; i < 4; ++i) af[i] = *(const f16x8*)(rA + cur * 4096 + i * 512);
#pragma unroll
    for (int i = 0; i < 4; ++i) bf[i] = *(const f16x8*)(rB + cur * 4096 + i * 512);
#pragma unroll
    for (int mi = 0; mi < 4; ++mi)
#pragma unroll
      for (int ni = 0; ni < 4; ++ni)
        acc[mi][ni] = __builtin_amdgcn_mfma_f32_16x16x32_f16(af[mi], bf[ni],
                                                             acc[mi][ni], 0, 0, 0);
    if (more) {
      if (AF32) {
        *(uint4*)(sA0 + nxt * 4096) = pk8(a0, a1);
        *(uint4*)(sA0 + nxt * 4096 + 2048) = pk8(a2, a3);
      }
      if (BF32) {
        *(uint4*)(sB0 + nxt * 4096) = pk8(b0, b1);
        *(uint4*)(sB0 + nxt * 4096 + 2048) = pk8(b2, b3);
      }
    }
    __syncthreads();  // drains vmcnt (gld16) + lgkm; tile t+1 ready, t reads done
  }

  // C/D layout (HW-verified): col = lane&15, row = (lane>>4)*4 + r
  const int rowBase = tm * 128 + wm * 64 + ((lane >> 4) << 2);
  const int colBase = tn * 128 + wn * 64 + (lane & 15);

  if (MODE == 1) {
    float* Out = (float*)Out_;
    float bv[4];
#pragma unroll
    for (int ni = 0; ni < 4; ++ni) bv[ni] = bias[colBase + ni * 16];
#pragma unroll
    for (int mi = 0; mi < 4; ++mi)
#pragma unroll
      for (int r = 0; r < 4; ++r) {
        size_t ro = (size_t)(rowBase + mi * 16 + r) * Nn;
#pragma unroll
        for (int ni = 0; ni < 4; ++ni)
          Out[ro + colBase + ni * 16] = acc[mi][ni][r] + bv[ni];
      }
  } else {
    u16* Out = (u16*)Out_;
    const int sel = colBase >> 9;
    const int hh = (colBase >> 6) & 7;
    const int ddb = lane & 15;
#pragma unroll
    for (int mi = 0; mi < 4; ++mi)
#pragma unroll
      for (int r = 0; r < 4; ++r) {
        float s = acc[mi][0][r] * acc[mi][0][r] + acc[mi][1][r] * acc[mi][1][r] +
                  acc[mi][2][r] * acc[mi][2][r] + acc[mi][3][r] * acc[mi][3][r];
        s += __shfl_xor(s, 1);
        s += __shfl_xor(s, 2);
        s += __shfl_xor(s, 4);
        s += __shfl_xor(s, 8);
        float inv = 1.0f / fmaxf(sqrtf(s), 1e-12f);
        const int m = rowBase + mi * 16 + r;
        const int bb = m >> 13, tt = (m >> 10) & 7, pix = m & 1023;
        const int fr = ((sel * 2 + bb) * 8 + tt) * 8 + hh;
        size_t base = (((size_t)fr) << 16) + (size_t)pix * 64 + ddb;
#pragma unroll
        for (int ni = 0; ni < 4; ++ni)
          Out[base + ni * 16] = f2h(acc[mi][ni][r] * inv);
      }
  }
}

// Dots-only cost volume: 1 thread per px-head, full 64ch, no shfl.
// qf planar [sel][b][t][h][1024px][64] f16.
// corr[tok][512] f16, col = h*64 + du*8 + dv (du,dv<7 data; pads zero).
// 512 blocks (128 frame-heads x 4 groups of 8 q-rows) x 256 threads.
// LDS: 14 staged k-rows x 32px x 128B = 57344B, XOR-swizzled.
__global__ __launch_bounds__(256) void dots(
    const u16* __restrict__ qf, u16* __restrict__ corr) {
  __shared__ __align__(16) u16 kst[448 * 64];
  const int tid = threadIdx.x;
  const int bid = ((int)blockIdx.x & 7) * 64 + ((int)blockIdx.x >> 3);  // XCD
  const int fr = bid >> 2, grp = bid & 3;
  const int h = fr & 7, t = (fr >> 3) & 7, b = fr >> 6;
  const int t1 = (t < 7) ? t + 1 : 7;
  const int y0 = grp * 8;

  const u16* kbase = qf + (((size_t)(((2 + b) * 8 + t1) * 8 + h)) << 16);
  {
    const int ppx = tid >> 3;
    const int slot = tid & 7;
#pragma unroll
    for (int pass = 0; pass < 14; ++pass) {
      int gy = y0 - 3 + pass;
      uint4 v = make_uint4(0, 0, 0, 0);
      if ((unsigned)gy < 32u)
        v = *(const uint4*)(kbase + (size_t)(gy * 32 + ppx) * 64 + slot * 8);
      int pl = pass * 32 + ppx;
      *(uint4*)((char*)kst + pl * 128 + ((slot * 16) ^ ((pl & 7) << 4))) = v;
    }
  }

  const int px = grp * 256 + tid;
  const int x = tid & 31, yloc = tid >> 5;
  const u16* qp = qf + (((size_t)fr) << 16) + (size_t)px * 64;
  u32 qw[32];
#pragma unroll
  for (int j = 0; j < 8; ++j) {
    uint4 v = *(const uint4*)(qp + j * 8);
    qw[j * 4 + 0] = v.x; qw[j * 4 + 1] = v.y;
    qw[j * 4 + 2] = v.z; qw[j * 4 + 3] = v.w;
  }
  __syncthreads();

  u16* mp = corr + (size_t)((b * 8 + t) * 1024 + px) * 512 + h * 64;
  for (int du = 0; du < 7; ++du) {
    const int rlbase = (yloc + du) * 32;
    float f[7];
#pragma unroll
    for (int dv = 0; dv < 7; ++dv) {
      int xx = x + dv - 3;
      int xc = xx < 0 ? 0 : (xx > 31 ? 31 : xx);
      int pl = rlbase + xc;
      const char* kr = (const char*)kst + pl * 128;
      const int swz = (pl & 7) << 4;
      float s0 = 0.f, s1 = 0.f, s2 = 0.f, s3 = 0.f;
#pragma unroll
      for (int j = 0; j < 8; ++j) {
        uint4 v = *(const uint4*)(kr + ((j * 16) ^ swz));
        s0 = dot2u(qw[j * 4 + 0], v.x, s0);
        s1 = dot2u(qw[j * 4 + 1], v.y, s1);
        s2 = dot2u(qw[j * 4 + 2], v.z, s2);
        s3 = dot2u(qw[j * 4 + 3], v.w, s3);
      }
      float s = (s0 + s1) + (s2 + s3);
      f[dv] = ((unsigned)xx < 32u) ? s : 0.f;
    }
    uint4 o;
    o.x = pkh(f[0], f[1]); o.y = pkh(f[2], f[3]);
    o.z = pkh(f[4], f[5]); o.w = pkh(f[6], 0.f);
    *(uint4*)(mp + du * 8) = o;
  }
  *(uint4*)(mp + 56) = make_uint4(0, 0, 0, 0);
}

extern "C" void kernel_launch(void* const* d_in, const int* in_sizes, int n_in,
                              void* d_out, int out_size, void* d_ws, size_t ws_size,
                              hipStream_t stream) {
  const float* x      = (const float*)d_in[0];  // [2,8192,512] f32
  const float* w_qk   = (const float*)d_in[1];  // [1024,512]   f32
  const float* w_corr = (const float*)d_in[2];  // [64,49]      f32
  const float* b_corr = (const float*)d_in[3];  // [64]         f32
  const float* w_proj = (const float*)d_in[4];  // [512,512]    f32
  const float* b_proj = (const float*)d_in[5];  // [512]        f32
  float* out = (float*)d_out;                   // [2,8192,512] f32

  // ws (48MB): [0,16MB) corr [16384][512] f16; [16MB,48MB) qf planar f16,
  // later aliased by W2 (512KB) + cvec after dots.
  u16* corr = (u16*)d_ws;
  u16* qf   = corr + (size_t)16384 * 512;
  u16* W2   = qf;                         // alias: qf dead after dots
  float* cvec = (float*)(qf + (size_t)512 * 512);

  // qk projection (f32 operands, fused convert) + per-head L2 norm -> qf
  gemm<0, 1, 1, 8><<<dim3(1024), dim3(256), 0, stream>>>(
      x, w_qk, nullptr, qf, 1024, 512);
  // cost-volume dots -> corr [16384][512]
  dots<<<dim3(512), dim3(256), 0, stream>>>(qf, corr);
  // fused corr->out weights (into qf region, safe after dots)
  w2prep<<<dim3(512), dim3(512), 0, stream>>>(w_proj, w_corr, b_corr, b_proj,
                                              W2, cvec);
  // out = corr @ W2^T + cvec  (K=512, f16 gld16 both operands)
  gemm<1, 0, 0, 4><<<dim3(512), dim3(256), 0, stream>>>(
      corr, W2, cvec, out, 512, 512);
}

// Round 10
// 79.472 us; speedup vs baseline: 1.4277x; 1.0536x over previous
//
#include <hip/hip_runtime.h>

typedef unsigned int u32;
typedef unsigned short u16;
typedef __fp16 h2 __attribute__((ext_vector_type(2)));
typedef __fp16 f16x8 __attribute__((ext_vector_type(8)));
typedef float f32x4 __attribute__((ext_vector_type(4)));

#define DEVFN static __device__ __forceinline__

DEVFN u32 pkh(float a, float b) {
  return __builtin_bit_cast(u32, __builtin_amdgcn_cvt_pkrtz(a, b));
}
DEVFN u16 f2h(float f) { __fp16 h = (__fp16)f; return __builtin_bit_cast(u16, h); }

#if __has_builtin(__builtin_amdgcn_fdot2)
DEVFN float dot2u(u32 a, u32 b, float c) {
  return __builtin_amdgcn_fdot2(__builtin_bit_cast(h2, a),
                                __builtin_bit_cast(h2, b), c, false);
}
#else
DEVFN float dot2u(u32 a, u32 b, float c) {
  h2 x = __builtin_bit_cast(h2, a), y = __builtin_bit_cast(h2, b);
  return c + (float)x[0] * (float)y[0] + (float)x[1] * (float)y[1];
}
#endif

DEVFN uint4 pk8(f32x4 lo, f32x4 hi) {
  uint4 o;
  o.x = pkh(lo.x, lo.y); o.y = pkh(lo.z, lo.w);
  o.z = pkh(hi.x, hi.y); o.w = pkh(hi.z, hi.w);
  return o;
}

// C = A @ B^T. Prefetch-distance-2 software pipeline (issue-early / write-late):
// regs hold tile t+1 (loaded one full iteration ago) -> ds_write to buf[cur^1]
// -> issue loads t+2 -> ds_read+MFMA buf[cur] -> barrier. HBM latency hidden.
// F32: operands f32 (convert at ds_write). else f16 passthrough. K%32==0.
// MODE 0: L2-normalize each aligned 64-col group; write f16 PLANAR qf
//         [sel][b][t][h][1024px][64]  (fr = ((sel*2+b)*8+t)*8+h); Nn=1024
// MODE 1: add f32 bias[col]; Out = f32 row-major [M][Nn]
// Tiles: BM=BN=128, BK=32; 4 waves (2x2), 4x4 frags of mfma 16x16x32 f16.
template <int MODE, int F32, int TN>
__global__ __launch_bounds__(256) void gemm(
    const void* __restrict__ A_, const void* __restrict__ B_,
    const float* __restrict__ bias, void* __restrict__ Out_,
    int Nn, int K) {
  __shared__ u16 As[2][4096];
  __shared__ u16 Bs[2][4096];
  const int tid = threadIdx.x;
  const int lane = tid & 63;
  const int w = tid >> 6;
  const int wm = w >> 1, wn = w & 1;
  const int nwg = (int)gridDim.x;
  const int wg = ((int)blockIdx.x & 7) * (nwg >> 3) + ((int)blockIdx.x >> 3);
  const int tm = wg / TN, tn = wg % TN;

  const float* Af = (const float*)A_;
  const float* Bf = (const float*)B_;
  const u16* Ah = (const u16*)A_;
  const u16* Bh = (const u16*)B_;

  // staging geometry: thread covers rows {rr, rr+64}, 8 k-elems at slot s
  const int rr = tid >> 2;
  const int s8 = (tid & 3) << 3;
  const size_t offA = (size_t)(tm * 128 + rr) * K + s8;
  const size_t offB = (size_t)(tn * 128 + rr) * K + s8;
  const int wofs = rr * 32 + s8;           // elem offset; row+64 => +2048

  // fragment read bases: 16-dim idx = lane&15, k-group = lane>>4
  const int rofsA = ((wm * 64 + (lane & 15)) << 5) + ((lane >> 4) << 3);
  const int rofsB = ((wn * 64 + (lane & 15)) << 5) + ((lane >> 4) << 3);

  f32x4 acc[4][4] = {};
  const int KT = K >> 5;

  f32x4 a0, a1, a2, a3, b0, b1, b2, b3;   // F32 staging regs
  uint4 ha0, ha1, hb0, hb1;               // f16 staging regs

#define ISSUE(t)                                                          \
  {                                                                       \
    const size_t oa = offA + (size_t)(t) * 32;                            \
    const size_t ob = offB + (size_t)(t) * 32;                            \
    if (F32) {                                                            \
      a0 = *(const f32x4*)(Af + oa);                                      \
      a1 = *(const f32x4*)(Af + oa + 4);                                  \
      a2 = *(const f32x4*)(Af + oa + (size_t)64 * K);                     \
      a3 = *(const f32x4*)(Af + oa + (size_t)64 * K + 4);                 \
      b0 = *(const f32x4*)(Bf + ob);                                      \
      b1 = *(const f32x4*)(Bf + ob + 4);                                  \
      b2 = *(const f32x4*)(Bf + ob + (size_t)64 * K);                     \
      b3 = *(const f32x4*)(Bf + ob + (size_t)64 * K + 4);                 \
    } else {                                                              \
      ha0 = *(const uint4*)(Ah + oa);                                     \
      ha1 = *(const uint4*)(Ah + oa + (size_t)64 * K);                    \
      hb0 = *(const uint4*)(Bh + ob);                                     \
      hb1 = *(const uint4*)(Bh + ob + (size_t)64 * K);                    \
    }                                                                     \
  }

#define WRITE(bufi)                                                       \
  {                                                                       \
    u16* da = &As[bufi][wofs];                                            \
    u16* db = &Bs[bufi][wofs];                                            \
    if (F32) {                                                            \
      *(uint4*)da = pk8(a0, a1);                                          \
      *(uint4*)(da + 2048) = pk8(a2, a3);                                 \
      *(uint4*)db = pk8(b0, b1);                                          \
      *(uint4*)(db + 2048) = pk8(b2, b3);                                 \
    } else {                                                              \
      *(uint4*)da = ha0;                                                  \
      *(uint4*)(da + 2048) = ha1;                                         \
      *(uint4*)db = hb0;                                                  \
      *(uint4*)(db + 2048) = hb1;                                         \
    }                                                                     \
  }

  // prologue: tile 0 staged; tile 1 loads in flight
  ISSUE(0)
  WRITE(0)
  ISSUE(1)
  __syncthreads();

  for (int kt = 0; kt < KT; ++kt) {
    const int cur = kt & 1;
    if (kt + 1 < KT) {
      WRITE(cur ^ 1)               // regs loaded a full iteration ago
      if (kt + 2 < KT) ISSUE(kt + 2)
    }
    f16x8 af[4], bf[4];
#pragma unroll
    for (int i = 0; i < 4; ++i) af[i] = *(const f16x8*)(&As[cur][rofsA + i * 512]);
#pragma unroll
    for (int i = 0; i < 4; ++i) bf[i] = *(const f16x8*)(&Bs[cur][rofsB + i * 512]);
#pragma unroll
    for (int mi = 0; mi < 4; ++mi)
#pragma unroll
      for (int ni = 0; ni < 4; ++ni)
        acc[mi][ni] = __builtin_amdgcn_mfma_f32_16x16x32_f16(af[mi], bf[ni],
                                                             acc[mi][ni], 0, 0, 0);
    __syncthreads();  // t's reads done; t+1's writes visible
  }
#undef ISSUE
#undef WRITE

  // C/D layout (HW-verified): col = lane&15, row = (lane>>4)*4 + r
  const int rowBase = tm * 128 + wm * 64 + ((lane >> 4) << 2);
  const int colBase = tn * 128 + wn * 64 + (lane & 15);

  if (MODE == 1) {
    float* Out = (float*)Out_;
    float bv[4];
#pragma unroll
    for (int ni = 0; ni < 4; ++ni) bv[ni] = bias[colBase + ni * 16];
#pragma unroll
    for (int mi = 0; mi < 4; ++mi)
#pragma unroll
      for (int r = 0; r < 4; ++r) {
        size_t ro = (size_t)(rowBase + mi * 16 + r) * Nn;
#pragma unroll
        for (int ni = 0; ni < 4; ++ni)
          Out[ro + colBase + ni * 16] = acc[mi][ni][r] + bv[ni];
      }
  } else {
    u16* Out = (u16*)Out_;
    const int sel = colBase >> 9;
    const int hh = (colBase >> 6) & 7;
    const int ddb = lane & 15;
#pragma unroll
    for (int mi = 0; mi < 4; ++mi)
#pragma unroll
      for (int r = 0; r < 4; ++r) {
        float s = acc[mi][0][r] * acc[mi][0][r] + acc[mi][1][r] * acc[mi][1][r] +
                  acc[mi][2][r] * acc[mi][2][r] + acc[mi][3][r] * acc[mi][3][r];
        s += __shfl_xor(s, 1);
        s += __shfl_xor(s, 2);
        s += __shfl_xor(s, 4);
        s += __shfl_xor(s, 8);
        float inv = 1.0f / fmaxf(sqrtf(s), 1e-12f);
        const int m = rowBase + mi * 16 + r;
        const int bb = m >> 13, tt = (m >> 10) & 7, pix = m & 1023;
        const int fr = ((sel * 2 + bb) * 8 + tt) * 8 + hh;
        size_t base = (((size_t)fr) << 16) + (size_t)pix * 64 + ddb;
#pragma unroll
        for (int ni = 0; ni < 4; ++ni)
          Out[base + ni * 16] = f2h(acc[mi][ni][r] * inv);
      }
  }
}

// Merged: blocks 0..511 = cost-volume dots; blocks 512..1023 = W2/cvec prep.
// dots: qf planar [sel][b][t][h][1024px][64] f16 -> corr[tok][512] f16
//       (col = h*64 + du*8 + dv; du,dv<7 data, pads zero).
// w2:   W2[o][h*64+du*8+dv] = sum_c w_proj[o][h*64+c]*w_corr[c][du*7+dv];
//       cvec[o] = b_proj[o] + sum_c' w_proj[o][c']*b_corr[c'&63]
__global__ __launch_bounds__(256) void dots_w2(
    const u16* __restrict__ qf, u16* __restrict__ corr,
    const float* __restrict__ wp, const float* __restrict__ wc,
    const float* __restrict__ bc, const float* __restrict__ bp,
    u16* __restrict__ W2, float* __restrict__ cvec) {
  __shared__ __align__(16) u16 smem[448 * 64];  // 56KB (dots); w2 reuses 14.6KB
  const int tid = threadIdx.x;

  if ((int)blockIdx.x >= 512) {
    // ---- W2 prep ----
    const int o = (int)blockIdx.x - 512;
    float* wcl = (float*)smem;       // [64*49]
    float* wpl = wcl + 3136;         // [512]
    for (int i = tid; i < 3136; i += 256) wcl[i] = wc[i];
    wpl[tid] = wp[o * 512 + tid];
    wpl[tid + 256] = wp[o * 512 + tid + 256];
    __syncthreads();
#pragma unroll
    for (int pass = 0; pass < 2; ++pass) {
      const int idx = pass * 256 + tid;
      const int hh = idx >> 6, r = idx & 63, du = r >> 3, dv = r & 7;
      float sv = 0.f;
      if (du < 7 && dv < 7) {
#pragma unroll
        for (int c = 0; c < 64; ++c)
          sv += wpl[hh * 64 + c] * wcl[c * 49 + du * 7 + dv];
      }
      W2[o * 512 + idx] = f2h(sv);
    }
    if (tid < 64) {
      float p = 0.f;
#pragma unroll
      for (int g = 0; g < 8; ++g) p += wpl[g * 64 + tid];
      p *= bc[tid];
      p += __shfl_xor(p, 1); p += __shfl_xor(p, 2); p += __shfl_xor(p, 4);
      p += __shfl_xor(p, 8); p += __shfl_xor(p, 16); p += __shfl_xor(p, 32);
      if (tid == 0) cvec[o] = p + bp[o];
    }
    return;
  }

  // ---- dots ----
  u16* kst = smem;
  const int bid = ((int)blockIdx.x & 7) * 64 + ((int)blockIdx.x >> 3);  // XCD
  const int fr = bid >> 2, grp = bid & 3;
  const int h = fr & 7, t = (fr >> 3) & 7, b = fr >> 6;
  const int t1 = (t < 7) ? t + 1 : 7;
  const int y0 = grp * 8;

  const u16* kbase = qf + (((size_t)(((2 + b) * 8 + t1) * 8 + h)) << 16);
  {
    const int ppx = tid >> 3;
    const int slot = tid & 7;
#pragma unroll
    for (int pass = 0; pass < 14; ++pass) {
      int gy = y0 - 3 + pass;
      uint4 v = make_uint4(0, 0, 0, 0);
      if ((unsigned)gy < 32u)
        v = *(const uint4*)(kbase + (size_t)(gy * 32 + ppx) * 64 + slot * 8);
      int pl = pass * 32 + ppx;
      *(uint4*)((char*)kst + pl * 128 + ((slot * 16) ^ ((pl & 7) << 4))) = v;
    }
  }

  const int px = grp * 256 + tid;
  const int x = tid & 31, yloc = tid >> 5;
  const u16* qp = qf + (((size_t)fr) << 16) + (size_t)px * 64;
  u32 qw[32];
#pragma unroll
  for (int j = 0; j < 8; ++j) {
    uint4 v = *(const uint4*)(qp + j * 8);
    qw[j * 4 + 0] = v.x; qw[j * 4 + 1] = v.y;
    qw[j * 4 + 2] = v.z; qw[j * 4 + 3] = v.w;
  }
  __syncthreads();

  u16* mp = corr + (size_t)((b * 8 + t) * 1024 + px) * 512 + h * 64;
  for (int du = 0; du < 7; ++du) {
    const int rlbase = (yloc + du) * 32;
    float f[7];
#pragma unroll
    for (int dv = 0; dv < 7; ++dv) {
      int xx = x + dv - 3;
      int xc = xx < 0 ? 0 : (xx > 31 ? 31 : xx);
      int pl = rlbase + xc;
      const char* kr = (const char*)kst + pl * 128;
      const int swz = (pl & 7) << 4;
      float s0 = 0.f, s1 = 0.f, s2 = 0.f, s3 = 0.f;
#pragma unroll
      for (int j = 0; j < 8; ++j) {
        uint4 v = *(const uint4*)(kr + ((j * 16) ^ swz));
        s0 = dot2u(qw[j * 4 + 0], v.x, s0);
        s1 = dot2u(qw[j * 4 + 1], v.y, s1);
        s2 = dot2u(qw[j * 4 + 2], v.z, s2);
        s3 = dot2u(qw[j * 4 + 3], v.w, s3);
      }
      float s = (s0 + s1) + (s2 + s3);
      f[dv] = ((unsigned)xx < 32u) ? s : 0.f;
    }
    uint4 o;
    o.x = pkh(f[0], f[1]); o.y = pkh(f[2], f[3]);
    o.z = pkh(f[4], f[5]); o.w = pkh(f[6], 0.f);
    *(uint4*)(mp + du * 8) = o;
  }
  *(uint4*)(mp + 56) = make_uint4(0, 0, 0, 0);
}

extern "C" void kernel_launch(void* const* d_in, const int* in_sizes, int n_in,
                              void* d_out, int out_size, void* d_ws, size_t ws_size,
                              hipStream_t stream) {
  const float* x      = (const float*)d_in[0];  // [2,8192,512] f32
  const float* w_qk   = (const float*)d_in[1];  // [1024,512]   f32
  const float* w_corr = (const float*)d_in[2];  // [64,49]      f32
  const float* b_corr = (const float*)d_in[3];  // [64]         f32
  const float* w_proj = (const float*)d_in[4];  // [512,512]    f32
  const float* b_proj = (const float*)d_in[5];  // [512]        f32
  float* out = (float*)d_out;                   // [2,8192,512] f32

  // ws (>=256MB): corr 16MB | qf 32MB | W2 512KB | cvec 2KB
  u16* corr = (u16*)d_ws;
  u16* qf   = corr + (size_t)16384 * 512;
  u16* W2   = qf + (size_t)16384 * 1024;
  float* cvec = (float*)(W2 + (size_t)512 * 512);

  // qk projection (f32 operands, fused convert) + per-head L2 norm -> qf
  gemm<0, 1, 8><<<dim3(1024), dim3(256), 0, stream>>>(
      x, w_qk, nullptr, qf, 1024, 512);
  // cost-volume dots -> corr; W2/cvec prep (merged launch)
  dots_w2<<<dim3(1024), dim3(256), 0, stream>>>(qf, corr, w_proj, w_corr,
                                                b_corr, b_proj, W2, cvec);
  // out = corr @ W2^T + cvec  (K=512, f16)
  gemm<1, 0, 4><<<dim3(512), dim3(256), 0, stream>>>(
      corr, W2, cvec, out, 512, 512);
}

// Round 11
// 78.890 us; speedup vs baseline: 1.4382x; 1.0074x over previous
//
#include <hip/hip_runtime.h>

typedef unsigned int u32;
typedef unsigned short u16;
typedef __fp16 h2 __attribute__((ext_vector_type(2)));
typedef __fp16 f16x8 __attribute__((ext_vector_type(8)));
typedef float f32x4 __attribute__((ext_vector_type(4)));

#define DEVFN static __device__ __forceinline__

DEVFN u32 pkh(float a, float b) {
  return __builtin_bit_cast(u32, __builtin_amdgcn_cvt_pkrtz(a, b));
}
DEVFN u16 f2h(float f) { __fp16 h = (__fp16)f; return __builtin_bit_cast(u16, h); }

#if __has_builtin(__builtin_amdgcn_fdot2)
DEVFN float dot2u(u32 a, u32 b, float c) {
  return __builtin_amdgcn_fdot2(__builtin_bit_cast(h2, a),
                                __builtin_bit_cast(h2, b), c, false);
}
#else
DEVFN float dot2u(u32 a, u32 b, float c) {
  h2 x = __builtin_bit_cast(h2, a), y = __builtin_bit_cast(h2, b);
  return c + (float)x[0] * (float)y[0] + (float)x[1] * (float)y[1];
}
#endif

DEVFN uint4 pk8(f32x4 lo, f32x4 hi) {
  uint4 o;
  o.x = pkh(lo.x, lo.y); o.y = pkh(lo.z, lo.w);
  o.z = pkh(hi.x, hi.y); o.w = pkh(hi.z, hi.w);
  return o;
}

DEVFN void gld16(const u16* g, u16* l) {
  __builtin_amdgcn_global_load_lds(
      (const __attribute__((address_space(1))) u32*)g,
      (__attribute__((address_space(3))) u32*)l, 16, 0, 0);
}

DEVFN void waitv0() { asm volatile("s_waitcnt vmcnt(0)" ::: "memory"); }
DEVFN void waitl0() { asm volatile("s_waitcnt lgkmcnt(0)" ::: "memory"); }
// raw barrier: NO compiler-added vmcnt drain -> prefetch loads stay in flight
DEVFN void rbar() {
  __builtin_amdgcn_sched_barrier(0);
  __builtin_amdgcn_s_barrier();
  __builtin_amdgcn_sched_barrier(0);
}

// C = A @ B^T, 2-phase raw-barrier pipeline (T3-min + T4 + T5).
// F32=1: A,B f32; reg-staged write-late (loads span 1 full iteration + barrier).
// F32=0: A,B f16; gld16 direct-to-LDS (guide's verified 2-phase recipe).
// MODE 0: L2-normalize each aligned 64-col group; write f16 PLANAR qf
//         [sel][b][t][h][1024px][64]  (fr = ((sel*2+b)*8+t)*8+h); Nn=1024
// MODE 1: add f32 bias[col]; Out = f32 row-major [M][Nn]
// Tiles: BM=BN=128, BK=32; 4 waves (2x2), 4x4 frags of mfma 16x16x32 f16.
template <int MODE, int F32, int TN>
__global__ __launch_bounds__(256) void gemm(
    const void* __restrict__ A_, const void* __restrict__ B_,
    const float* __restrict__ bias, void* __restrict__ Out_,
    int Nn, int K) {
  __shared__ u16 As[2][4096];
  __shared__ u16 Bs[2][4096];
  const int tid = threadIdx.x;
  const int lane = tid & 63;
  const int w = tid >> 6;
  const int wm = w >> 1, wn = w & 1;
  const int nwg = (int)gridDim.x;
  const int wg = ((int)blockIdx.x & 7) * (nwg >> 3) + ((int)blockIdx.x >> 3);
  const int tm = wg / TN, tn = wg % TN;

  const float* Af = (const float*)A_;
  const float* Bf = (const float*)B_;
  const u16* Ah = (const u16*)A_;
  const u16* Bh = (const u16*)B_;

  // reg-staging geometry (F32): thread rows {rr, rr+64}, 8 k-elems
  const int rr = tid >> 2;
  const int s8 = (tid & 3) << 3;
  const size_t offA = (size_t)(tm * 128 + rr) * K + s8;
  const size_t offB = (size_t)(tn * 128 + rr) * K + s8;
  const int wofs = rr * 32 + s8;

  // gld16 geometry (f16): wave w covers rows w*32..w*32+31
  const int sr = w * 32 + (lane >> 2);
  const int sc = (lane & 3) << 3;
  const u16* gA = Ah + (size_t)(tm * 128 + sr) * K + sc;
  const u16* gB = Bh + (size_t)(tn * 128 + sr) * K + sc;

  // fragment read bases
  const int rofsA = ((wm * 64 + (lane & 15)) << 5) + ((lane >> 4) << 3);
  const int rofsB = ((wn * 64 + (lane & 15)) << 5) + ((lane >> 4) << 3);

  f32x4 acc[4][4] = {};
  const int KT = K >> 5;

  f32x4 a0, a1, a2, a3, b0, b1, b2, b3;  // F32 staging regs

#define LOADF(t)                                                          \
  {                                                                       \
    const size_t oa = offA + (size_t)(t) * 32;                            \
    const size_t ob = offB + (size_t)(t) * 32;                            \
    a0 = *(const f32x4*)(Af + oa);                                        \
    a1 = *(const f32x4*)(Af + oa + 4);                                    \
    a2 = *(const f32x4*)(Af + oa + (size_t)64 * K);                       \
    a3 = *(const f32x4*)(Af + oa + (size_t)64 * K + 4);                   \
    b0 = *(const f32x4*)(Bf + ob);                                        \
    b1 = *(const f32x4*)(Bf + ob + 4);                                    \
    b2 = *(const f32x4*)(Bf + ob + (size_t)64 * K);                       \
    b3 = *(const f32x4*)(Bf + ob + (size_t)64 * K + 4);                   \
  }
#define WRITEF(bufi)                                                      \
  {                                                                       \
    u16* da = &As[bufi][wofs];                                            \
    u16* db = &Bs[bufi][wofs];                                            \
    *(uint4*)da = pk8(a0, a1);                                            \
    *(uint4*)(da + 2048) = pk8(a2, a3);                                   \
    *(uint4*)db = pk8(b0, b1);                                            \
    *(uint4*)(db + 2048) = pk8(b2, b3);                                   \
  }
#define STAGEH(bufi, t)                                                   \
  {                                                                       \
    gld16(gA + (size_t)(t) * 32, &As[bufi][w * 1024]);                    \
    gld16(gA + (size_t)(t) * 32 + (size_t)16 * K, &As[bufi][w * 1024 + 512]); \
    gld16(gB + (size_t)(t) * 32, &Bs[bufi][w * 1024]);                    \
    gld16(gB + (size_t)(t) * 32 + (size_t)16 * K, &Bs[bufi][w * 1024 + 512]); \
  }

  // ---- prologue ----
  if (F32) {
    LOADF(0)
    WRITEF(0)      // compiler inserts vmcnt before the cvt uses
    LOADF(1)       // tile 1 loads in flight across the barrier
    waitl0();      // ds_writes visible to all waves
  } else {
    STAGEH(0, 0)
    waitv0();      // gld16 DMA complete
  }
  rbar();

  // ---- main loop: raw barrier, loads cross it in flight ----
  for (int kt = 0; kt < KT; ++kt) {
    const int cur = kt & 1;
    f16x8 af[4], bf[4];
    if (F32) {
      // ds_read current tile first (DS pipe busy while vmcnt waits resolve)
#pragma unroll
      for (int i = 0; i < 4; ++i) af[i] = *(const f16x8*)(&As[cur][rofsA + i * 512]);
#pragma unroll
      for (int i = 0; i < 4; ++i) bf[i] = *(const f16x8*)(&Bs[cur][rofsB + i * 512]);
      if (kt + 1 < KT) {
        WRITEF(cur ^ 1)              // regs = tile kt+1, loaded one iter ago
        if (kt + 2 < KT) LOADF(kt + 2)
      }
    } else {
      if (kt + 1 < KT) STAGEH(cur ^ 1, kt + 1)  // gld16 issue, awaited post-MFMA
#pragma unroll
      for (int i = 0; i < 4; ++i) af[i] = *(const f16x8*)(&As[cur][rofsA + i * 512]);
#pragma unroll
      for (int i = 0; i < 4; ++i) bf[i] = *(const f16x8*)(&Bs[cur][rofsB + i * 512]);
    }
    __builtin_amdgcn_s_setprio(1);
#pragma unroll
    for (int mi = 0; mi < 4; ++mi)
#pragma unroll
      for (int ni = 0; ni < 4; ++ni)
        acc[mi][ni] = __builtin_amdgcn_mfma_f32_16x16x32_f16(af[mi], bf[ni],
                                                             acc[mi][ni], 0, 0, 0);
    __builtin_amdgcn_s_setprio(0);
    if (F32) waitl0();   // ds_writes of tile kt+1 complete (long done under MFMA)
    else waitv0();       // gld16 of tile kt+1 complete
    rbar();
  }
#undef LOADF
#undef WRITEF
#undef STAGEH

  // C/D layout (HW-verified): col = lane&15, row = (lane>>4)*4 + r
  const int rowBase = tm * 128 + wm * 64 + ((lane >> 4) << 2);
  const int colBase = tn * 128 + wn * 64 + (lane & 15);

  if (MODE == 1) {
    float* Out = (float*)Out_;
    float bv[4];
#pragma unroll
    for (int ni = 0; ni < 4; ++ni) bv[ni] = bias[colBase + ni * 16];
#pragma unroll
    for (int mi = 0; mi < 4; ++mi)
#pragma unroll
      for (int r = 0; r < 4; ++r) {
        size_t ro = (size_t)(rowBase + mi * 16 + r) * Nn;
#pragma unroll
        for (int ni = 0; ni < 4; ++ni)
          Out[ro + colBase + ni * 16] = acc[mi][ni][r] + bv[ni];
      }
  } else {
    u16* Out = (u16*)Out_;
    const int sel = colBase >> 9;
    const int hh = (colBase >> 6) & 7;
    const int ddb = lane & 15;
#pragma unroll
    for (int mi = 0; mi < 4; ++mi)
#pragma unroll
      for (int r = 0; r < 4; ++r) {
        float s = acc[mi][0][r] * acc[mi][0][r] + acc[mi][1][r] * acc[mi][1][r] +
                  acc[mi][2][r] * acc[mi][2][r] + acc[mi][3][r] * acc[mi][3][r];
        s += __shfl_xor(s, 1);
        s += __shfl_xor(s, 2);
        s += __shfl_xor(s, 4);
        s += __shfl_xor(s, 8);
        float inv = 1.0f / fmaxf(sqrtf(s), 1e-12f);
        const int m = rowBase + mi * 16 + r;
        const int bb = m >> 13, tt = (m >> 10) & 7, pix = m & 1023;
        const int fr = ((sel * 2 + bb) * 8 + tt) * 8 + hh;
        size_t base = (((size_t)fr) << 16) + (size_t)pix * 64 + ddb;
#pragma unroll
        for (int ni = 0; ni < 4; ++ni)
          Out[base + ni * 16] = f2h(acc[mi][ni][r] * inv);
      }
  }
}

// Merged: blocks 0..511 = cost-volume dots; blocks 512..1023 = W2/cvec prep.
__global__ __launch_bounds__(256) void dots_w2(
    const u16* __restrict__ qf, u16* __restrict__ corr,
    const float* __restrict__ wp, const float* __restrict__ wc,
    const float* __restrict__ bc, const float* __restrict__ bp,
    u16* __restrict__ W2, float* __restrict__ cvec) {
  __shared__ __align__(16) u16 smem[448 * 64];
  const int tid = threadIdx.x;

  if ((int)blockIdx.x >= 512) {
    const int o = (int)blockIdx.x - 512;
    float* wcl = (float*)smem;
    float* wpl = wcl + 3136;
    for (int i = tid; i < 3136; i += 256) wcl[i] = wc[i];
    wpl[tid] = wp[o * 512 + tid];
    wpl[tid + 256] = wp[o * 512 + tid + 256];
    __syncthreads();
#pragma unroll
    for (int pass = 0; pass < 2; ++pass) {
      const int idx = pass * 256 + tid;
      const int hh = idx >> 6, r = idx & 63, du = r >> 3, dv = r & 7;
      float sv = 0.f;
      if (du < 7 && dv < 7) {
#pragma unroll
        for (int c = 0; c < 64; ++c)
          sv += wpl[hh * 64 + c] * wcl[c * 49 + du * 7 + dv];
      }
      W2[o * 512 + idx] = f2h(sv);
    }
    if (tid < 64) {
      float p = 0.f;
#pragma unroll
      for (int g = 0; g < 8; ++g) p += wpl[g * 64 + tid];
      p *= bc[tid];
      p += __shfl_xor(p, 1); p += __shfl_xor(p, 2); p += __shfl_xor(p, 4);
      p += __shfl_xor(p, 8); p += __shfl_xor(p, 16); p += __shfl_xor(p, 32);
      if (tid == 0) cvec[o] = p + bp[o];
    }
    return;
  }

  u16* kst = smem;
  const int bid = ((int)blockIdx.x & 7) * 64 + ((int)blockIdx.x >> 3);  // XCD
  const int fr = bid >> 2, grp = bid & 3;
  const int h = fr & 7, t = (fr >> 3) & 7, b = fr >> 6;
  const int t1 = (t < 7) ? t + 1 : 7;
  const int y0 = grp * 8;

  const u16* kbase = qf + (((size_t)(((2 + b) * 8 + t1) * 8 + h)) << 16);
  {
    const int ppx = tid >> 3;
    const int slot = tid & 7;
#pragma unroll
    for (int pass = 0; pass < 14; ++pass) {
      int gy = y0 - 3 + pass;
      uint4 v = make_uint4(0, 0, 0, 0);
      if ((unsigned)gy < 32u)
        v = *(const uint4*)(kbase + (size_t)(gy * 32 + ppx) * 64 + slot * 8);
      int pl = pass * 32 + ppx;
      *(uint4*)((char*)kst + pl * 128 + ((slot * 16) ^ ((pl & 7) << 4))) = v;
    }
  }

  const int px = grp * 256 + tid;
  const int x = tid & 31, yloc = tid >> 5;
  const u16* qp = qf + (((size_t)fr) << 16) + (size_t)px * 64;
  u32 qw[32];
#pragma unroll
  for (int j = 0; j < 8; ++j) {
    uint4 v = *(const uint4*)(qp + j * 8);
    qw[j * 4 + 0] = v.x; qw[j * 4 + 1] = v.y;
    qw[j * 4 + 2] = v.z; qw[j * 4 + 3] = v.w;
  }
  __syncthreads();

  u16* mp = corr + (size_t)((b * 8 + t) * 1024 + px) * 512 + h * 64;
  for (int du = 0; du < 7; ++du) {
    const int rlbase = (yloc + du) * 32;
    float f[7];
#pragma unroll
    for (int dv = 0; dv < 7; ++dv) {
      int xx = x + dv - 3;
      int xc = xx < 0 ? 0 : (xx > 31 ? 31 : xx);
      int pl = rlbase + xc;
      const char* kr = (const char*)kst + pl * 128;
      const int swz = (pl & 7) << 4;
      float s0 = 0.f, s1 = 0.f, s2 = 0.f, s3 = 0.f;
#pragma unroll
      for (int j = 0; j < 8; ++j) {
        uint4 v = *(const uint4*)(kr + ((j * 16) ^ swz));
        s0 = dot2u(qw[j * 4 + 0], v.x, s0);
        s1 = dot2u(qw[j * 4 + 1], v.y, s1);
        s2 = dot2u(qw[j * 4 + 2], v.z, s2);
        s3 = dot2u(qw[j * 4 + 3], v.w, s3);
      }
      float s = (s0 + s1) + (s2 + s3);
      f[dv] = ((unsigned)xx < 32u) ? s : 0.f;
    }
    uint4 o;
    o.x = pkh(f[0], f[1]); o.y = pkh(f[2], f[3]);
    o.z = pkh(f[4], f[5]); o.w = pkh(f[6], 0.f);
    *(uint4*)(mp + du * 8) = o;
  }
  *(uint4*)(mp + 56) = make_uint4(0, 0, 0, 0);
}

extern "C" void kernel_launch(void* const* d_in, const int* in_sizes, int n_in,
                              void* d_out, int out_size, void* d_ws, size_t ws_size,
                              hipStream_t stream) {
  const float* x      = (const float*)d_in[0];  // [2,8192,512] f32
  const float* w_qk   = (const float*)d_in[1];  // [1024,512]   f32
  const float* w_corr = (const float*)d_in[2];  // [64,49]      f32
  const float* b_corr = (const float*)d_in[3];  // [64]         f32
  const float* w_proj = (const float*)d_in[4];  // [512,512]    f32
  const float* b_proj = (const float*)d_in[5];  // [512]        f32
  float* out = (float*)d_out;                   // [2,8192,512] f32

  u16* corr = (u16*)d_ws;
  u16* qf   = corr + (size_t)16384 * 512;
  u16* W2   = qf + (size_t)16384 * 1024;
  float* cvec = (float*)(W2 + (size_t)512 * 512);

  // qk projection (f32 operands, fused convert, raw-barrier pipeline) + L2 norm
  gemm<0, 1, 8><<<dim3(1024), dim3(256), 0, stream>>>(
      x, w_qk, nullptr, qf, 1024, 512);
  // cost-volume dots -> corr; W2/cvec prep (merged launch)
  dots_w2<<<dim3(1024), dim3(256), 0, stream>>>(qf, corr, w_proj, w_corr,
                                                b_corr, b_proj, W2, cvec);
  // out = corr @ W2^T + cvec  (K=512, f16 gld16 2-phase)
  gemm<1, 0, 4><<<dim3(512), dim3(256), 0, stream>>>(
      corr, W2, cvec, out, 512, 512);
}